// Round 2
// baseline (1216.123 us; speedup 1.0000x reference)
//
#include <hip/hip_runtime.h>
#include <hip/hip_bf16.h>

#define N_NODES 50000
#define N_EDGES 320000
#define IN_FEAT 128
#define HIDDEN  256
#define NCLS    40
#define BN_EPS  1e-5f

// ---------------- CSR build ----------------
__global__ void k_hist(const int* __restrict__ dst, int* __restrict__ counts) {
    int e = blockIdx.x * blockDim.x + threadIdx.x;
    if (e < N_EDGES) atomicAdd(&counts[dst[e]], 1);
}

__global__ void k_scan(const int* __restrict__ counts, int* __restrict__ row_ptr,
                       int* __restrict__ cursor) {
    __shared__ int s[1024];
    const int tid = threadIdx.x;
    const int CH = (N_NODES + 1023) / 1024;  // 49
    int lo = tid * CH;
    int hi = lo + CH; if (hi > N_NODES) hi = N_NODES;
    if (lo > N_NODES) lo = N_NODES;
    int sum = 0;
    for (int i = lo; i < hi; i++) sum += counts[i];
    s[tid] = sum;
    __syncthreads();
    for (int off = 1; off < 1024; off <<= 1) {
        int v = (tid >= off) ? s[tid - off] : 0;
        __syncthreads();
        s[tid] += v;
        __syncthreads();
    }
    int run = s[tid] - sum;  // exclusive prefix of this chunk
    for (int i = lo; i < hi; i++) {
        row_ptr[i] = run;
        cursor[i] = run;
        run += counts[i];
    }
    if (tid == 1023) row_ptr[N_NODES] = s[1023];
}

__global__ void k_dinv(const int* __restrict__ counts, float* __restrict__ dinv) {
    int i = blockIdx.x * blockDim.x + threadIdx.x;
    if (i < N_NODES) dinv[i] = rsqrtf(1.0f + (float)counts[i]);  // deg = 1 + indeg
}

__global__ void k_scatter(const int* __restrict__ src, const int* __restrict__ dst,
                          int* __restrict__ cursor, int* __restrict__ ssrc) {
    int e = blockIdx.x * blockDim.x + threadIdx.x;
    if (e < N_EDGES) {
        int d = dst[e];
        int p = atomicAdd(&cursor[d], 1);
        ssrc[p] = src[e];
    }
}

// ---------------- GEMM: C[N,M] = A[N,K] @ B[K,M], fp32 ----------------
__global__ void k_gemm(const float* __restrict__ A, const float* __restrict__ B,
                       float* __restrict__ C, int K, int M) {
    __shared__ float As[16][17];
    __shared__ float Bs[16][17];
    const int tx = threadIdx.x, ty = threadIdx.y;
    const int row = blockIdx.y * 16 + ty;      // N = 50000 is a multiple of 16
    const int col = blockIdx.x * 16 + tx;
    float acc = 0.f;
    for (int k0 = 0; k0 < K; k0 += 16) {
        As[ty][tx] = A[row * K + k0 + tx];
        Bs[ty][tx] = (col < M) ? B[(k0 + ty) * M + col] : 0.f;
        __syncthreads();
#pragma unroll
        for (int k = 0; k < 16; k++) acc += As[ty][k] * Bs[k][tx];
        __syncthreads();
    }
    if (col < M) C[row * M + col] = acc;
}

// ---------------- Aggregation (gather over CSR), F = 256 ----------------
__global__ void k_agg256(const float4* __restrict__ XW, const int* __restrict__ row_ptr,
                         const int* __restrict__ ssrc, const float* __restrict__ dinv,
                         const float* __restrict__ bias, float4* __restrict__ H) {
    const int wave = threadIdx.x >> 6;
    const int lane = threadIdx.x & 63;
    const int node = blockIdx.x * 4 + wave;   // 50000 = 12500 * 4
    const float dd = dinv[node];
    const float sw = dd * dd;
    float4 v = XW[node * 64 + lane];
    float4 acc;
    acc.x = sw * v.x; acc.y = sw * v.y; acc.z = sw * v.z; acc.w = sw * v.w;
    const int s0 = row_ptr[node], s1 = row_ptr[node + 1];
    for (int j = s0; j < s1; j++) {
        const int s = ssrc[j];
        const float w = dinv[s] * dd;
        float4 u = XW[s * 64 + lane];
        acc.x += w * u.x; acc.y += w * u.y; acc.z += w * u.z; acc.w += w * u.w;
    }
    const int f = lane * 4;
    acc.x += bias[f + 0];
    acc.y += bias[f + 1];
    acc.z += bias[f + 2];
    acc.w += bias[f + 3];
    H[node * 64 + lane] = acc;
}

// ---------------- Aggregation, F = 40 (one wave per node) -----
__global__ void k_agg40(const float* __restrict__ XW, const int* __restrict__ row_ptr,
                        const int* __restrict__ ssrc, const float* __restrict__ dinv,
                        const float* __restrict__ bias, float* __restrict__ H) {
    const int wave = threadIdx.x >> 6;
    const int lane = threadIdx.x & 63;
    const int node = blockIdx.x * 4 + wave;
    const float dd = dinv[node];
    float acc = 0.f;
    if (lane < NCLS) acc = dd * dd * XW[node * NCLS + lane];
    const int s0 = row_ptr[node], s1 = row_ptr[node + 1];
    for (int j = s0; j < s1; j++) {
        const int s = ssrc[j];
        const float w = dinv[s] * dd;
        if (lane < NCLS) acc += w * XW[s * NCLS + lane];
    }
    if (lane < NCLS) H[node * NCLS + lane] = acc + bias[lane];
}

// ---------------- BatchNorm (training stats) + ReLU ----------------
__global__ void k_bnstats(const float* __restrict__ H, float* __restrict__ gsum,
                          float* __restrict__ gsq) {
    const int f = threadIdx.x;       // 256 features
    const int r0 = blockIdx.x * 64;
    int r1 = r0 + 64; if (r1 > N_NODES) r1 = N_NODES;
    float s = 0.f, q = 0.f;
    for (int r = r0; r < r1; r++) {
        float v = H[r * HIDDEN + f];
        s += v; q += v * v;
    }
    atomicAdd(&gsum[f], s);
    atomicAdd(&gsq[f], q);
}

__global__ void k_bnprep(const float* __restrict__ gsum, const float* __restrict__ gsq,
                         const float* __restrict__ g, const float* __restrict__ be,
                         float* __restrict__ scale, float* __restrict__ shift) {
    const int f = threadIdx.x;
    const float inv_n = 1.0f / (float)N_NODES;
    float mean = gsum[f] * inv_n;
    float var = gsq[f] * inv_n - mean * mean;
    var = fmaxf(var, 0.f);
    float sc = g[f] * rsqrtf(var + BN_EPS);
    scale[f] = sc;
    shift[f] = be[f] - mean * sc;
}

__global__ void k_bnapply(float4* __restrict__ H, const float* __restrict__ scale,
                          const float* __restrict__ shift) {
    const int i = blockIdx.x * blockDim.x + threadIdx.x;  // over N*64 float4s
    if (i >= N_NODES * 64) return;
    const int f = (i & 63) * 4;
    float4 v = H[i];
    v.x = fmaxf(v.x * scale[f + 0] + shift[f + 0], 0.f);
    v.y = fmaxf(v.y * scale[f + 1] + shift[f + 1], 0.f);
    v.z = fmaxf(v.z * scale[f + 2] + shift[f + 2], 0.f);
    v.w = fmaxf(v.w * scale[f + 3] + shift[f + 3], 0.f);
    H[i] = v;
}

// ---------------- log_softmax over 40 classes ----------------
__global__ void k_lsm(const float* __restrict__ H3, float* __restrict__ out) {
    const int n = blockIdx.x * blockDim.x + threadIdx.x;
    if (n >= N_NODES) return;
    const float* row = H3 + n * NCLS;
    float m = -1e30f;
    for (int c = 0; c < NCLS; c++) m = fmaxf(m, row[c]);
    float s = 0.f;
    for (int c = 0; c < NCLS; c++) s += expf(row[c] - m);
    const float lse = m + logf(s);
    for (int c = 0; c < NCLS; c++) out[n * NCLS + c] = row[c] - lse;
}

extern "C" void kernel_launch(void* const* d_in, const int* in_sizes, int n_in,
                              void* d_out, int out_size, void* d_ws, size_t ws_size,
                              hipStream_t stream) {
    const float* x   = (const float*)d_in[0];
    const int*   ei  = (const int*)d_in[1];
    const float* W1  = (const float*)d_in[2];
    const float* b1  = (const float*)d_in[3];
    const float* g1  = (const float*)d_in[4];
    const float* be1 = (const float*)d_in[5];
    const float* W2  = (const float*)d_in[6];
    const float* b2  = (const float*)d_in[7];
    const float* g2  = (const float*)d_in[8];
    const float* be2 = (const float*)d_in[9];
    const float* W3  = (const float*)d_in[10];
    const float* b3  = (const float*)d_in[11];
    float* out = (float*)d_out;

    const int* e_src = ei;             // edge_index[0]
    const int* e_dst = ei + N_EDGES;   // edge_index[1]

    // ---- workspace layout (bytes) ----
    char* w = (char*)d_ws;
    float* XW     = (float*)w;                 w += (size_t)N_NODES * HIDDEN * 4;  // 51.2 MB
    float* H      = (float*)w;                 w += (size_t)N_NODES * HIDDEN * 4;  // 51.2 MB
    float* dinv   = (float*)w;                 w += (size_t)N_NODES * 4;
    int*   counts = (int*)w;                   w += (size_t)N_NODES * 4;
    int*   rowp   = (int*)w;                   w += (size_t)(N_NODES + 4) * 4;
    int*   cursor = (int*)w;                   w += (size_t)N_NODES * 4;
    int*   ssrc   = (int*)w;                   w += (size_t)N_EDGES * 4;
    float* gsum   = (float*)w;                 w += 256 * 4;
    float* gsq    = (float*)w;                 w += 256 * 4;
    float* scale  = (float*)w;                 w += 256 * 4;
    float* shift  = (float*)w;                 w += 256 * 4;

    const int EB = (N_EDGES + 255) / 256;
    const int NB = (N_NODES + 255) / 256;

    // ---- CSR build + normalization ----
    hipMemsetAsync(counts, 0, (size_t)N_NODES * 4, stream);
    k_hist<<<EB, 256, 0, stream>>>(e_dst, counts);
    k_scan<<<1, 1024, 0, stream>>>(counts, rowp, cursor);
    k_dinv<<<NB, 256, 0, stream>>>(counts, dinv);
    k_scatter<<<EB, 256, 0, stream>>>(e_src, e_dst, cursor, ssrc);

    dim3 gB(16, 16);

    // ---- layer 1 ----
    k_gemm<<<dim3(HIDDEN / 16, N_NODES / 16), gB, 0, stream>>>(x, W1, XW, IN_FEAT, HIDDEN);
    k_agg256<<<N_NODES / 4, 256, 0, stream>>>((const float4*)XW, rowp, ssrc, dinv, b1, (float4*)H);
    hipMemsetAsync(gsum, 0, 2 * 256 * 4, stream);
    k_bnstats<<<(N_NODES + 63) / 64, 256, 0, stream>>>(H, gsum, gsq);
    k_bnprep<<<1, 256, 0, stream>>>(gsum, gsq, g1, be1, scale, shift);
    k_bnapply<<<(N_NODES * 64 + 255) / 256, 256, 0, stream>>>((float4*)H, scale, shift);

    // ---- layer 2 ----
    k_gemm<<<dim3(HIDDEN / 16, N_NODES / 16), gB, 0, stream>>>(H, W2, XW, HIDDEN, HIDDEN);
    k_agg256<<<N_NODES / 4, 256, 0, stream>>>((const float4*)XW, rowp, ssrc, dinv, b2, (float4*)H);
    hipMemsetAsync(gsum, 0, 2 * 256 * 4, stream);
    k_bnstats<<<(N_NODES + 63) / 64, 256, 0, stream>>>(H, gsum, gsq);
    k_bnprep<<<1, 256, 0, stream>>>(gsum, gsq, g2, be2, scale, shift);
    k_bnapply<<<(N_NODES * 64 + 255) / 256, 256, 0, stream>>>((float4*)H, scale, shift);

    // ---- output layer ----
    k_gemm<<<dim3((NCLS + 15) / 16, N_NODES / 16), gB, 0, stream>>>(H, W3, XW, HIDDEN, NCLS);
    float* H3 = H;  // safe: k_agg40 reads XW, writes H3
    k_agg40<<<N_NODES / 4, 256, 0, stream>>>(XW, rowp, ssrc, dinv, b3, H3);
    k_lsm<<<(N_NODES + 255) / 256, 256, 0, stream>>>(H3, out);
}

// Round 3
// 699.775 us; speedup vs baseline: 1.7379x; 1.7379x over previous
//
#include <hip/hip_runtime.h>
#include <hip/hip_bf16.h>

#define N_NODES 50000
#define N_EDGES 320000
#define IN_FEAT 128
#define HIDDEN  256
#define NCLS    40
#define BN_EPS  1e-5f

// ---------------- CSR build ----------------
__global__ void k_hist(const int* __restrict__ dst, int* __restrict__ counts) {
    int e = blockIdx.x * blockDim.x + threadIdx.x;
    if (e < N_EDGES) atomicAdd(&counts[dst[e]], 1);
}

__global__ void k_scan(const int* __restrict__ counts, int* __restrict__ row_ptr,
                       int* __restrict__ cursor) {
    __shared__ int s[1024];
    const int tid = threadIdx.x;
    const int CH = (N_NODES + 1023) / 1024;  // 49
    int lo = tid * CH;
    int hi = lo + CH; if (hi > N_NODES) hi = N_NODES;
    if (lo > N_NODES) lo = N_NODES;
    int sum = 0;
    for (int i = lo; i < hi; i++) sum += counts[i];
    s[tid] = sum;
    __syncthreads();
    for (int off = 1; off < 1024; off <<= 1) {
        int v = (tid >= off) ? s[tid - off] : 0;
        __syncthreads();
        s[tid] += v;
        __syncthreads();
    }
    int run = s[tid] - sum;  // exclusive prefix of this chunk
    for (int i = lo; i < hi; i++) {
        row_ptr[i] = run;
        cursor[i] = run;
        run += counts[i];
    }
    if (tid == 1023) row_ptr[N_NODES] = s[1023];
}

__global__ void k_dinv(const int* __restrict__ counts, float* __restrict__ dinv) {
    int i = blockIdx.x * blockDim.x + threadIdx.x;
    if (i < N_NODES) dinv[i] = rsqrtf(1.0f + (float)counts[i]);  // deg = 1 + indeg
}

__global__ void k_scatter(const int* __restrict__ src, const int* __restrict__ dst,
                          int* __restrict__ cursor, int* __restrict__ ssrc) {
    int e = blockIdx.x * blockDim.x + threadIdx.x;
    if (e < N_EDGES) {
        int d = dst[e];
        int p = atomicAdd(&cursor[d], 1);
        ssrc[p] = src[e];
    }
}

// ---------------- Register-tiled GEMM: C[N,M] = A[N,K] @ B[K,M] ----------------
// 64x64 tile, BK=16, 256 threads, 4x4 acc/thread.
#define BM 64
#define BN 64
#define BK 16

__global__ __launch_bounds__(256) void k_gemm_rt(const float* __restrict__ A,
                                                 const float* __restrict__ B,
                                                 float* __restrict__ C,
                                                 int N, int K, int M) {
    __shared__ float Ast[BK][BM + 4];  // A tile, transposed: Ast[k][m]
    __shared__ float Bs[BK][BN + 4];   // B tile: Bs[k][n]
    const int t  = threadIdx.x;
    const int tx = t & 15;             // output col group (4 cols)
    const int ty = t >> 4;             // output row group (4 rows)
    const int row0 = blockIdx.y * BM;
    const int col0 = blockIdx.x * BN;

    // staging indices
    const int lrow = t >> 2;           // 0..63: A row within tile
    const int lk4  = (t & 3) * 4;      // k offset {0,4,8,12}
    const int brow = t >> 4;           // 0..15: B k within tile
    const int bcol = (t & 15) * 4;     // B col offset

    float acc[4][4] = {};

    for (int k0 = 0; k0 < K; k0 += BK) {
        // stage A (float4 row read -> transposed LDS write)
        float4 av = make_float4(0.f, 0.f, 0.f, 0.f);
        const int ar = row0 + lrow;
        if (ar < N) av = *(const float4*)(A + (size_t)ar * K + k0 + lk4);
        Ast[lk4 + 0][lrow] = av.x;
        Ast[lk4 + 1][lrow] = av.y;
        Ast[lk4 + 2][lrow] = av.z;
        Ast[lk4 + 3][lrow] = av.w;
        // stage B
        float4 bv = make_float4(0.f, 0.f, 0.f, 0.f);
        const int bc = col0 + bcol;
        if (bc + 3 < M) {
            bv = *(const float4*)(B + (size_t)(k0 + brow) * M + bc);
        } else {
            float tmp[4] = {0.f, 0.f, 0.f, 0.f};
            for (int j = 0; j < 4; j++)
                if (bc + j < M) tmp[j] = B[(size_t)(k0 + brow) * M + bc + j];
            bv = make_float4(tmp[0], tmp[1], tmp[2], tmp[3]);
        }
        *(float4*)&Bs[brow][bcol] = bv;
        __syncthreads();

#pragma unroll
        for (int k = 0; k < BK; k++) {
            float4 a4 = *(const float4*)&Ast[k][ty * 4];
            float4 b4 = *(const float4*)&Bs[k][tx * 4];
            const float av_[4] = {a4.x, a4.y, a4.z, a4.w};
            const float bv_[4] = {b4.x, b4.y, b4.z, b4.w};
#pragma unroll
            for (int i = 0; i < 4; i++)
#pragma unroll
                for (int j = 0; j < 4; j++)
                    acc[i][j] = fmaf(av_[i], bv_[j], acc[i][j]);
        }
        __syncthreads();
    }

    // store
#pragma unroll
    for (int i = 0; i < 4; i++) {
        const int r = row0 + ty * 4 + i;
        if (r >= N) continue;
        const int c = col0 + tx * 4;
        if (c + 3 < M) {
            *(float4*)(C + (size_t)r * M + c) =
                make_float4(acc[i][0], acc[i][1], acc[i][2], acc[i][3]);
        } else {
            for (int j = 0; j < 4; j++)
                if (c + j < M) C[(size_t)r * M + c + j] = acc[i][j];
        }
    }
}

// ---------------- Aggregation (gather over CSR), F = 256 ----------------
__global__ void k_agg256(const float4* __restrict__ XW, const int* __restrict__ row_ptr,
                         const int* __restrict__ ssrc, const float* __restrict__ dinv,
                         const float* __restrict__ bias, float4* __restrict__ H) {
    const int wave = threadIdx.x >> 6;
    const int lane = threadIdx.x & 63;
    const int node = blockIdx.x * 4 + wave;   // 50000 = 12500 * 4
    const float dd = dinv[node];
    const float sw = dd * dd;
    float4 v = XW[node * 64 + lane];
    float4 acc;
    acc.x = sw * v.x; acc.y = sw * v.y; acc.z = sw * v.z; acc.w = sw * v.w;
    const int s0 = row_ptr[node], s1 = row_ptr[node + 1];
    for (int j = s0; j < s1; j++) {
        const int s = ssrc[j];
        const float w = dinv[s] * dd;
        float4 u = XW[s * 64 + lane];
        acc.x += w * u.x; acc.y += w * u.y; acc.z += w * u.z; acc.w += w * u.w;
    }
    const int f = lane * 4;
    acc.x += bias[f + 0];
    acc.y += bias[f + 1];
    acc.z += bias[f + 2];
    acc.w += bias[f + 3];
    H[node * 64 + lane] = acc;
}

// ---------------- Aggregation, F = 40 (one wave per node) -----
__global__ void k_agg40(const float* __restrict__ XW, const int* __restrict__ row_ptr,
                        const int* __restrict__ ssrc, const float* __restrict__ dinv,
                        const float* __restrict__ bias, float* __restrict__ H) {
    const int wave = threadIdx.x >> 6;
    const int lane = threadIdx.x & 63;
    const int node = blockIdx.x * 4 + wave;
    const float dd = dinv[node];
    float acc = 0.f;
    if (lane < NCLS) acc = dd * dd * XW[node * NCLS + lane];
    const int s0 = row_ptr[node], s1 = row_ptr[node + 1];
    for (int j = s0; j < s1; j++) {
        const int s = ssrc[j];
        const float w = dinv[s] * dd;
        if (lane < NCLS) acc += w * XW[s * NCLS + lane];
    }
    if (lane < NCLS) H[node * NCLS + lane] = acc + bias[lane];
}

// ---------------- BatchNorm (training stats) + ReLU ----------------
__global__ void k_bnstats(const float* __restrict__ H, float* __restrict__ gsum,
                          float* __restrict__ gsq) {
    const int f = threadIdx.x;       // 256 features
    const int r0 = blockIdx.x * 64;
    int r1 = r0 + 64; if (r1 > N_NODES) r1 = N_NODES;
    float s = 0.f, q = 0.f;
    for (int r = r0; r < r1; r++) {
        float v = H[r * HIDDEN + f];
        s += v; q += v * v;
    }
    atomicAdd(&gsum[f], s);
    atomicAdd(&gsq[f], q);
}

__global__ void k_bnprep(const float* __restrict__ gsum, const float* __restrict__ gsq,
                         const float* __restrict__ g, const float* __restrict__ be,
                         float* __restrict__ scale, float* __restrict__ shift) {
    const int f = threadIdx.x;
    const float inv_n = 1.0f / (float)N_NODES;
    float mean = gsum[f] * inv_n;
    float var = gsq[f] * inv_n - mean * mean;
    var = fmaxf(var, 0.f);
    float sc = g[f] * rsqrtf(var + BN_EPS);
    scale[f] = sc;
    shift[f] = be[f] - mean * sc;
}

__global__ void k_bnapply(float4* __restrict__ H, const float* __restrict__ scale,
                          const float* __restrict__ shift) {
    const int i = blockIdx.x * blockDim.x + threadIdx.x;  // over N*64 float4s
    if (i >= N_NODES * 64) return;
    const int f = (i & 63) * 4;
    float4 v = H[i];
    v.x = fmaxf(v.x * scale[f + 0] + shift[f + 0], 0.f);
    v.y = fmaxf(v.y * scale[f + 1] + shift[f + 1], 0.f);
    v.z = fmaxf(v.z * scale[f + 2] + shift[f + 2], 0.f);
    v.w = fmaxf(v.w * scale[f + 3] + shift[f + 3], 0.f);
    H[i] = v;
}

// ---------------- log_softmax over 40 classes ----------------
__global__ void k_lsm(const float* __restrict__ H3, float* __restrict__ out) {
    const int n = blockIdx.x * blockDim.x + threadIdx.x;
    if (n >= N_NODES) return;
    const float* row = H3 + n * NCLS;
    float m = -1e30f;
    for (int c = 0; c < NCLS; c++) m = fmaxf(m, row[c]);
    float s = 0.f;
    for (int c = 0; c < NCLS; c++) s += expf(row[c] - m);
    const float lse = m + logf(s);
    for (int c = 0; c < NCLS; c++) out[n * NCLS + c] = row[c] - lse;
}

extern "C" void kernel_launch(void* const* d_in, const int* in_sizes, int n_in,
                              void* d_out, int out_size, void* d_ws, size_t ws_size,
                              hipStream_t stream) {
    const float* x   = (const float*)d_in[0];
    const int*   ei  = (const int*)d_in[1];
    const float* W1  = (const float*)d_in[2];
    const float* b1  = (const float*)d_in[3];
    const float* g1  = (const float*)d_in[4];
    const float* be1 = (const float*)d_in[5];
    const float* W2  = (const float*)d_in[6];
    const float* b2  = (const float*)d_in[7];
    const float* g2  = (const float*)d_in[8];
    const float* be2 = (const float*)d_in[9];
    const float* W3  = (const float*)d_in[10];
    const float* b3  = (const float*)d_in[11];
    float* out = (float*)d_out;

    const int* e_src = ei;             // edge_index[0]
    const int* e_dst = ei + N_EDGES;   // edge_index[1]

    // ---- workspace layout (bytes) ----
    char* w = (char*)d_ws;
    float* XW     = (float*)w;                 w += (size_t)N_NODES * HIDDEN * 4;  // 51.2 MB
    float* H      = (float*)w;                 w += (size_t)N_NODES * HIDDEN * 4;  // 51.2 MB
    float* dinv   = (float*)w;                 w += (size_t)N_NODES * 4;
    int*   counts = (int*)w;                   w += (size_t)N_NODES * 4;
    int*   rowp   = (int*)w;                   w += (size_t)(N_NODES + 4) * 4;
    int*   cursor = (int*)w;                   w += (size_t)N_NODES * 4;
    int*   ssrc   = (int*)w;                   w += (size_t)N_EDGES * 4;
    float* gsum   = (float*)w;                 w += 256 * 4;
    float* gsq    = (float*)w;                 w += 256 * 4;
    float* scale  = (float*)w;                 w += 256 * 4;
    float* shift  = (float*)w;                 w += 256 * 4;

    const int EB = (N_EDGES + 255) / 256;
    const int NB = (N_NODES + 255) / 256;
    const int GY = (N_NODES + BM - 1) / BM;  // 782

    // ---- CSR build + normalization ----
    hipMemsetAsync(counts, 0, (size_t)N_NODES * 4, stream);
    k_hist<<<EB, 256, 0, stream>>>(e_dst, counts);
    k_scan<<<1, 1024, 0, stream>>>(counts, rowp, cursor);
    k_dinv<<<NB, 256, 0, stream>>>(counts, dinv);
    k_scatter<<<EB, 256, 0, stream>>>(e_src, e_dst, cursor, ssrc);

    // ---- layer 1 ----
    k_gemm_rt<<<dim3(HIDDEN / BN, GY), 256, 0, stream>>>(x, W1, XW, N_NODES, IN_FEAT, HIDDEN);
    k_agg256<<<N_NODES / 4, 256, 0, stream>>>((const float4*)XW, rowp, ssrc, dinv, b1, (float4*)H);
    hipMemsetAsync(gsum, 0, 2 * 256 * 4, stream);
    k_bnstats<<<(N_NODES + 63) / 64, 256, 0, stream>>>(H, gsum, gsq);
    k_bnprep<<<1, 256, 0, stream>>>(gsum, gsq, g1, be1, scale, shift);
    k_bnapply<<<(N_NODES * 64 + 255) / 256, 256, 0, stream>>>((float4*)H, scale, shift);

    // ---- layer 2 ----
    k_gemm_rt<<<dim3(HIDDEN / BN, GY), 256, 0, stream>>>(H, W2, XW, N_NODES, HIDDEN, HIDDEN);
    k_agg256<<<N_NODES / 4, 256, 0, stream>>>((const float4*)XW, rowp, ssrc, dinv, b2, (float4*)H);
    hipMemsetAsync(gsum, 0, 2 * 256 * 4, stream);
    k_bnstats<<<(N_NODES + 63) / 64, 256, 0, stream>>>(H, gsum, gsq);
    k_bnprep<<<1, 256, 0, stream>>>(gsum, gsq, g2, be2, scale, shift);
    k_bnapply<<<(N_NODES * 64 + 255) / 256, 256, 0, stream>>>((float4*)H, scale, shift);

    // ---- output layer ----
    k_gemm_rt<<<dim3(1, GY), 256, 0, stream>>>(H, W3, XW, N_NODES, HIDDEN, NCLS);
    float* H3 = H;  // safe: k_agg40 reads XW, writes H3
    k_agg40<<<N_NODES / 4, 256, 0, stream>>>(XW, rowp, ssrc, dinv, b3, H3);
    k_lsm<<<(N_NODES + 255) / 256, 256, 0, stream>>>(H3, out);
}

// Round 4
// 594.510 us; speedup vs baseline: 2.0456x; 1.1771x over previous
//
#include <hip/hip_runtime.h>
#include <hip/hip_bf16.h>

#define N_NODES 50000
#define N_EDGES 320000
#define IN_FEAT 128
#define HIDDEN  256
#define NCLS    40
#define BN_EPS  1e-5f

#define SCAN_B  256
#define SCAN_NB ((N_NODES + SCAN_B - 1) / SCAN_B)   // 196

// ---------------- CSR build ----------------
__global__ void k_hist(const int* __restrict__ dst, int* __restrict__ counts) {
    int e = blockIdx.x * blockDim.x + threadIdx.x;
    if (e < N_EDGES) atomicAdd(&counts[dst[e]], 1);
}

// Per-chunk exclusive scan: rowp[i] = local exclusive prefix, partials[b] = chunk sum
__global__ __launch_bounds__(SCAN_B) void k_scan_local(const int* __restrict__ counts,
                                                       int* __restrict__ rowp,
                                                       int* __restrict__ partials) {
    __shared__ int s[SCAN_B];
    const int tid = threadIdx.x;
    const int i = blockIdx.x * SCAN_B + tid;
    int v = (i < N_NODES) ? counts[i] : 0;
    s[tid] = v;
    __syncthreads();
    for (int off = 1; off < SCAN_B; off <<= 1) {
        int t = (tid >= off) ? s[tid - off] : 0;
        __syncthreads();
        s[tid] += t;
        __syncthreads();
    }
    if (i < N_NODES) rowp[i] = s[tid] - v;  // exclusive
    if (tid == SCAN_B - 1) partials[blockIdx.x] = s[SCAN_B - 1];
}

// Block b adds sum(partials[0..b)) to its chunk; mirrors into cursor.
__global__ __launch_bounds__(SCAN_B) void k_scan_add(int* __restrict__ rowp,
                                                     int* __restrict__ cursor,
                                                     const int* __restrict__ partials) {
    __shared__ int s[SCAN_B];
    const int tid = threadIdx.x;
    const int b = blockIdx.x;
    int v = (tid < b) ? partials[tid] : 0;   // SCAN_NB <= 256
    s[tid] = v;
    __syncthreads();
    for (int off = SCAN_B / 2; off > 0; off >>= 1) {
        if (tid < off) s[tid] += s[tid + off];
        __syncthreads();
    }
    const int offset = s[0];
    const int i = b * SCAN_B + tid;
    if (i < N_NODES) {
        int r = rowp[i] + offset;
        rowp[i] = r;
        cursor[i] = r;
    }
    if (b == 0 && tid == 0) rowp[N_NODES] = N_EDGES;  // total = E always
}

__global__ void k_dinv(const int* __restrict__ counts, float* __restrict__ dinv) {
    int i = blockIdx.x * blockDim.x + threadIdx.x;
    if (i < N_NODES) dinv[i] = rsqrtf(1.0f + (float)counts[i]);  // deg = 1 + indeg
}

__global__ void k_scatter(const int* __restrict__ src, const int* __restrict__ dst,
                          int* __restrict__ cursor, int* __restrict__ ssrc) {
    int e = blockIdx.x * blockDim.x + threadIdx.x;
    if (e < N_EDGES) {
        int d = dst[e];
        int p = atomicAdd(&cursor[d], 1);
        ssrc[p] = src[e];
    }
}

// ---------------- Register-tiled GEMM: C[N,M] = A[N,K] @ B[K,M] ----------------
// 64x64 tile, BK=16, 256 threads, 4x4 acc/thread.
#define BM 64
#define BN 64
#define BK 16

__global__ __launch_bounds__(256) void k_gemm_rt(const float* __restrict__ A,
                                                 const float* __restrict__ B,
                                                 float* __restrict__ C,
                                                 int N, int K, int M) {
    __shared__ float Ast[BK][BM + 4];  // A tile, transposed: Ast[k][m]
    __shared__ float Bs[BK][BN + 4];   // B tile: Bs[k][n]
    const int t  = threadIdx.x;
    const int tx = t & 15;             // output col group (4 cols)
    const int ty = t >> 4;             // output row group (4 rows)
    const int row0 = blockIdx.y * BM;
    const int col0 = blockIdx.x * BN;

    const int lrow = t >> 2;           // 0..63: A row within tile
    const int lk4  = (t & 3) * 4;      // k offset {0,4,8,12}
    const int brow = t >> 4;           // 0..15: B k within tile
    const int bcol = (t & 15) * 4;     // B col offset

    float acc[4][4] = {};

    for (int k0 = 0; k0 < K; k0 += BK) {
        float4 av = make_float4(0.f, 0.f, 0.f, 0.f);
        const int ar = row0 + lrow;
        if (ar < N) av = *(const float4*)(A + (size_t)ar * K + k0 + lk4);
        Ast[lk4 + 0][lrow] = av.x;
        Ast[lk4 + 1][lrow] = av.y;
        Ast[lk4 + 2][lrow] = av.z;
        Ast[lk4 + 3][lrow] = av.w;
        float4 bv = make_float4(0.f, 0.f, 0.f, 0.f);
        const int bc = col0 + bcol;
        if (bc + 3 < M) {
            bv = *(const float4*)(B + (size_t)(k0 + brow) * M + bc);
        } else {
            float tmp[4] = {0.f, 0.f, 0.f, 0.f};
            for (int j = 0; j < 4; j++)
                if (bc + j < M) tmp[j] = B[(size_t)(k0 + brow) * M + bc + j];
            bv = make_float4(tmp[0], tmp[1], tmp[2], tmp[3]);
        }
        *(float4*)&Bs[brow][bcol] = bv;
        __syncthreads();

#pragma unroll
        for (int k = 0; k < BK; k++) {
            float4 a4 = *(const float4*)&Ast[k][ty * 4];
            float4 b4 = *(const float4*)&Bs[k][tx * 4];
            const float av_[4] = {a4.x, a4.y, a4.z, a4.w};
            const float bv_[4] = {b4.x, b4.y, b4.z, b4.w};
#pragma unroll
            for (int i = 0; i < 4; i++)
#pragma unroll
                for (int j = 0; j < 4; j++)
                    acc[i][j] = fmaf(av_[i], bv_[j], acc[i][j]);
        }
        __syncthreads();
    }

#pragma unroll
    for (int i = 0; i < 4; i++) {
        const int r = row0 + ty * 4 + i;
        if (r >= N) continue;
        const int c = col0 + tx * 4;
        if (c + 3 < M) {
            *(float4*)(C + (size_t)r * M + c) =
                make_float4(acc[i][0], acc[i][1], acc[i][2], acc[i][3]);
        } else {
            for (int j = 0; j < 4; j++)
                if (c + j < M) C[(size_t)r * M + c + j] = acc[i][j];
        }
    }
}

// ---------------- Aggregation (gather over CSR), F = 256 ----------------
__global__ void k_agg256(const float4* __restrict__ XW, const int* __restrict__ row_ptr,
                         const int* __restrict__ ssrc, const float* __restrict__ dinv,
                         const float* __restrict__ bias, float4* __restrict__ H) {
    const int wave = threadIdx.x >> 6;
    const int lane = threadIdx.x & 63;
    const int node = blockIdx.x * 4 + wave;   // 50000 = 12500 * 4
    const float dd = dinv[node];
    const float sw = dd * dd;
    float4 v = XW[node * 64 + lane];
    float4 acc;
    acc.x = sw * v.x; acc.y = sw * v.y; acc.z = sw * v.z; acc.w = sw * v.w;
    const int s0 = row_ptr[node], s1 = row_ptr[node + 1];
    for (int j = s0; j < s1; j++) {
        const int s = ssrc[j];
        const float w = dinv[s] * dd;
        float4 u = XW[s * 64 + lane];
        acc.x += w * u.x; acc.y += w * u.y; acc.z += w * u.z; acc.w += w * u.w;
    }
    const int f = lane * 4;
    acc.x += bias[f + 0];
    acc.y += bias[f + 1];
    acc.z += bias[f + 2];
    acc.w += bias[f + 3];
    H[node * 64 + lane] = acc;
}

// ---------------- Aggregation, F = 40 (one wave per node) -----
__global__ void k_agg40(const float* __restrict__ XW, const int* __restrict__ row_ptr,
                        const int* __restrict__ ssrc, const float* __restrict__ dinv,
                        const float* __restrict__ bias, float* __restrict__ H) {
    const int wave = threadIdx.x >> 6;
    const int lane = threadIdx.x & 63;
    const int node = blockIdx.x * 4 + wave;
    const float dd = dinv[node];
    float acc = 0.f;
    if (lane < NCLS) acc = dd * dd * XW[node * NCLS + lane];
    const int s0 = row_ptr[node], s1 = row_ptr[node + 1];
    for (int j = s0; j < s1; j++) {
        const int s = ssrc[j];
        const float w = dinv[s] * dd;
        if (lane < NCLS) acc += w * XW[s * NCLS + lane];
    }
    if (lane < NCLS) H[node * NCLS + lane] = acc + bias[lane];
}

// ---------------- BatchNorm (training stats) + ReLU ----------------
__global__ void k_bnstats(const float* __restrict__ H, float* __restrict__ gsum,
                          float* __restrict__ gsq) {
    const int f = threadIdx.x;       // 256 features
    const int r0 = blockIdx.x * 64;
    int r1 = r0 + 64; if (r1 > N_NODES) r1 = N_NODES;
    float s = 0.f, q = 0.f;
    for (int r = r0; r < r1; r++) {
        float v = H[r * HIDDEN + f];
        s += v; q += v * v;
    }
    atomicAdd(&gsum[f], s);
    atomicAdd(&gsq[f], q);
}

__global__ void k_bnprep(const float* __restrict__ gsum, const float* __restrict__ gsq,
                         const float* __restrict__ g, const float* __restrict__ be,
                         float* __restrict__ scale, float* __restrict__ shift) {
    const int f = threadIdx.x;
    const float inv_n = 1.0f / (float)N_NODES;
    float mean = gsum[f] * inv_n;
    float var = gsq[f] * inv_n - mean * mean;
    var = fmaxf(var, 0.f);
    float sc = g[f] * rsqrtf(var + BN_EPS);
    scale[f] = sc;
    shift[f] = be[f] - mean * sc;
}

__global__ void k_bnapply(float4* __restrict__ H, const float* __restrict__ scale,
                          const float* __restrict__ shift) {
    const int i = blockIdx.x * blockDim.x + threadIdx.x;  // over N*64 float4s
    if (i >= N_NODES * 64) return;
    const int f = (i & 63) * 4;
    float4 v = H[i];
    v.x = fmaxf(v.x * scale[f + 0] + shift[f + 0], 0.f);
    v.y = fmaxf(v.y * scale[f + 1] + shift[f + 1], 0.f);
    v.z = fmaxf(v.z * scale[f + 2] + shift[f + 2], 0.f);
    v.w = fmaxf(v.w * scale[f + 3] + shift[f + 3], 0.f);
    H[i] = v;
}

// ---------------- log_softmax over 40 classes ----------------
__global__ void k_lsm(const float* __restrict__ H3, float* __restrict__ out) {
    const int n = blockIdx.x * blockDim.x + threadIdx.x;
    if (n >= N_NODES) return;
    const float* row = H3 + n * NCLS;
    float m = -1e30f;
    for (int c = 0; c < NCLS; c++) m = fmaxf(m, row[c]);
    float s = 0.f;
    for (int c = 0; c < NCLS; c++) s += expf(row[c] - m);
    const float lse = m + logf(s);
    for (int c = 0; c < NCLS; c++) out[n * NCLS + c] = row[c] - lse;
}

extern "C" void kernel_launch(void* const* d_in, const int* in_sizes, int n_in,
                              void* d_out, int out_size, void* d_ws, size_t ws_size,
                              hipStream_t stream) {
    const float* x   = (const float*)d_in[0];
    const int*   ei  = (const int*)d_in[1];
    const float* W1  = (const float*)d_in[2];
    const float* b1  = (const float*)d_in[3];
    const float* g1  = (const float*)d_in[4];
    const float* be1 = (const float*)d_in[5];
    const float* W2  = (const float*)d_in[6];
    const float* b2  = (const float*)d_in[7];
    const float* g2  = (const float*)d_in[8];
    const float* be2 = (const float*)d_in[9];
    const float* W3  = (const float*)d_in[10];
    const float* b3  = (const float*)d_in[11];
    float* out = (float*)d_out;

    const int* e_src = ei;             // edge_index[0]
    const int* e_dst = ei + N_EDGES;   // edge_index[1]

    // ---- workspace layout (bytes) ----
    char* w = (char*)d_ws;
    float* XW     = (float*)w;                 w += (size_t)N_NODES * HIDDEN * 4;  // 51.2 MB
    float* H      = (float*)w;                 w += (size_t)N_NODES * HIDDEN * 4;  // 51.2 MB
    float* dinv   = (float*)w;                 w += (size_t)N_NODES * 4;
    int*   counts = (int*)w;                   w += (size_t)N_NODES * 4;
    int*   rowp   = (int*)w;                   w += (size_t)(N_NODES + 4) * 4;
    int*   cursor = (int*)w;                   w += (size_t)N_NODES * 4;
    int*   ssrc   = (int*)w;                   w += (size_t)N_EDGES * 4;
    int*   partials=(int*)w;                   w += 256 * 4;
    float* gsum   = (float*)w;                 w += 256 * 4;
    float* gsq    = (float*)w;                 w += 256 * 4;
    float* scale  = (float*)w;                 w += 256 * 4;
    float* shift  = (float*)w;                 w += 256 * 4;

    const int EB = (N_EDGES + 255) / 256;
    const int NB = (N_NODES + 255) / 256;
    const int GY = (N_NODES + BM - 1) / BM;  // 782

    // ---- CSR build + normalization ----
    hipMemsetAsync(counts, 0, (size_t)N_NODES * 4, stream);
    k_hist<<<EB, 256, 0, stream>>>(e_dst, counts);
    k_scan_local<<<SCAN_NB, SCAN_B, 0, stream>>>(counts, rowp, partials);
    k_scan_add<<<SCAN_NB, SCAN_B, 0, stream>>>(rowp, cursor, partials);
    k_dinv<<<NB, 256, 0, stream>>>(counts, dinv);
    k_scatter<<<EB, 256, 0, stream>>>(e_src, e_dst, cursor, ssrc);

    // ---- layer 1 ----
    k_gemm_rt<<<dim3(HIDDEN / BN, GY), 256, 0, stream>>>(x, W1, XW, N_NODES, IN_FEAT, HIDDEN);
    k_agg256<<<N_NODES / 4, 256, 0, stream>>>((const float4*)XW, rowp, ssrc, dinv, b1, (float4*)H);
    hipMemsetAsync(gsum, 0, 2 * 256 * 4, stream);
    k_bnstats<<<(N_NODES + 63) / 64, 256, 0, stream>>>(H, gsum, gsq);
    k_bnprep<<<1, 256, 0, stream>>>(gsum, gsq, g1, be1, scale, shift);
    k_bnapply<<<(N_NODES * 64 + 255) / 256, 256, 0, stream>>>((float4*)H, scale, shift);

    // ---- layer 2 ----
    k_gemm_rt<<<dim3(HIDDEN / BN, GY), 256, 0, stream>>>(H, W2, XW, N_NODES, HIDDEN, HIDDEN);
    k_agg256<<<N_NODES / 4, 256, 0, stream>>>((const float4*)XW, rowp, ssrc, dinv, b2, (float4*)H);
    hipMemsetAsync(gsum, 0, 2 * 256 * 4, stream);
    k_bnstats<<<(N_NODES + 63) / 64, 256, 0, stream>>>(H, gsum, gsq);
    k_bnprep<<<1, 256, 0, stream>>>(gsum, gsq, g2, be2, scale, shift);
    k_bnapply<<<(N_NODES * 64 + 255) / 256, 256, 0, stream>>>((float4*)H, scale, shift);

    // ---- output layer ----
    k_gemm_rt<<<dim3(1, GY), 256, 0, stream>>>(H, W3, XW, N_NODES, HIDDEN, NCLS);
    float* H3 = H;  // safe: k_agg40 reads XW, writes H3
    k_agg40<<<N_NODES / 4, 256, 0, stream>>>(XW, rowp, ssrc, dinv, b3, H3);
    k_lsm<<<(N_NODES + 255) / 256, 256, 0, stream>>>(H3, out);
}

// Round 5
// 455.436 us; speedup vs baseline: 2.6702x; 1.3054x over previous
//
#include <hip/hip_runtime.h>
#include <hip/hip_bf16.h>

#define N_NODES 50000
#define N_EDGES 320000
#define IN_FEAT 128
#define HIDDEN  256
#define NCLS    40
#define BN_EPS  1e-5f

#define SCAN_B  256
#define SCAN_NB ((N_NODES + SCAN_B - 1) / SCAN_B)   // 196

typedef __attribute__((ext_vector_type(8))) short bf16x8;
typedef __attribute__((ext_vector_type(4))) float f32x4;

__device__ __forceinline__ unsigned short f2bf(float f) {
    union { float f; unsigned u; } a; a.f = f;
    unsigned r = a.u + 0x7fff + ((a.u >> 16) & 1);   // RNE
    return (unsigned short)(r >> 16);
}
__device__ __forceinline__ float bf2f(unsigned short u) {
    union { unsigned u; float f; } a; a.u = ((unsigned)u) << 16;
    return a.f;
}

// ---------------- CSR build ----------------
__global__ void k_hist(const int* __restrict__ dst, int* __restrict__ counts) {
    int e = blockIdx.x * blockDim.x + threadIdx.x;
    if (e < N_EDGES) atomicAdd(&counts[dst[e]], 1);
}

__global__ __launch_bounds__(SCAN_B) void k_scan_local(const int* __restrict__ counts,
                                                       int* __restrict__ rowp,
                                                       int* __restrict__ partials) {
    __shared__ int s[SCAN_B];
    const int tid = threadIdx.x;
    const int i = blockIdx.x * SCAN_B + tid;
    int v = (i < N_NODES) ? counts[i] : 0;
    s[tid] = v;
    __syncthreads();
    for (int off = 1; off < SCAN_B; off <<= 1) {
        int t = (tid >= off) ? s[tid - off] : 0;
        __syncthreads();
        s[tid] += t;
        __syncthreads();
    }
    if (i < N_NODES) rowp[i] = s[tid] - v;  // exclusive
    if (tid == SCAN_B - 1) partials[blockIdx.x] = s[SCAN_B - 1];
}

__global__ __launch_bounds__(SCAN_B) void k_scan_add(int* __restrict__ rowp,
                                                     int* __restrict__ cursor,
                                                     const int* __restrict__ partials) {
    __shared__ int s[SCAN_B];
    const int tid = threadIdx.x;
    const int b = blockIdx.x;
    int v = (tid < b) ? partials[tid] : 0;   // SCAN_NB <= 256
    s[tid] = v;
    __syncthreads();
    for (int off = SCAN_B / 2; off > 0; off >>= 1) {
        if (tid < off) s[tid] += s[tid + off];
        __syncthreads();
    }
    const int offset = s[0];
    const int i = b * SCAN_B + tid;
    if (i < N_NODES) {
        int r = rowp[i] + offset;
        rowp[i] = r;
        cursor[i] = r;
    }
    if (b == 0 && tid == 0) rowp[N_NODES] = N_EDGES;
}

__global__ void k_dinv(const int* __restrict__ counts, float* __restrict__ dinv) {
    int i = blockIdx.x * blockDim.x + threadIdx.x;
    if (i < N_NODES) dinv[i] = rsqrtf(1.0f + (float)counts[i]);
}

__global__ void k_scatter(const int* __restrict__ src, const int* __restrict__ dst,
                          int* __restrict__ cursor, int* __restrict__ ssrc) {
    int e = blockIdx.x * blockDim.x + threadIdx.x;
    if (e < N_EDGES) {
        int d = dst[e];
        int p = atomicAdd(&cursor[d], 1);
        ssrc[p] = src[e];
    }
}

// ---------------- fp32 -> bf16 cast (x input) ----------------
__global__ void k_cvt_bf16(const float4* __restrict__ in, ushort4* __restrict__ outp, int n4) {
    int i = blockIdx.x * blockDim.x + threadIdx.x;
    if (i < n4) {
        float4 v = in[i];
        ushort4 o;
        o.x = f2bf(v.x); o.y = f2bf(v.y); o.z = f2bf(v.z); o.w = f2bf(v.w);
        outp[i] = o;
    }
}

// ---------------- pack W[K,M] fp32 -> MFMA B-frag layout bf16 ----------------
// Bp[nt][kt][lane][8]: lane l supplies B[kt*32+(l>>4)*8+j][nt*16+(l&15)]
__global__ void k_packB(const float* __restrict__ W, unsigned short* __restrict__ Bp,
                        int K, int M) {
    const int nt = blockIdx.x, kt = blockIdx.y, lane = threadIdx.x;
    const int nkt = gridDim.y;
    const int n = nt * 16 + (lane & 15);
    const int kb = kt * 32 + (lane >> 4) * 8;
    unsigned short* dst = Bp + (((size_t)nt * nkt + kt) * 64 + lane) * 8;
#pragma unroll
    for (int j = 0; j < 8; j++)
        dst[j] = (n < M) ? f2bf(W[(size_t)(kb + j) * M + n]) : (unsigned short)0;
}

// ---------------- MFMA GEMM: C[N,M] = A[N,K] @ B[K,M] ----------------
// A bf16 row-major, Bp packed frags. Wave computes 16 rows x NTILES*16 cols.
template <int K_, int NTILES, bool OUTF32>
__global__ __launch_bounds__(256) void k_gemm_mfma(const short* __restrict__ A,
                                                   const short* __restrict__ Bp,
                                                   void* __restrict__ Cv, int M) {
    const int wave = threadIdx.x >> 6;
    const int lane = threadIdx.x & 63;
    const int row0 = blockIdx.x * 16;
    const int ntile0 = wave * NTILES;
    constexpr int nkt = K_ / 32;
    const short* aptr = A + (size_t)(row0 + (lane & 15)) * K_ + (lane >> 4) * 8;
    f32x4 acc[NTILES] = {};
#pragma unroll
    for (int kt = 0; kt < nkt; kt++) {
        bf16x8 af = *(const bf16x8*)(aptr + kt * 32);
#pragma unroll
        for (int n = 0; n < NTILES; n++) {
            bf16x8 bfr = *(const bf16x8*)(Bp + (((size_t)(ntile0 + n) * nkt + kt) * 64 + lane) * 8);
            acc[n] = __builtin_amdgcn_mfma_f32_16x16x32_bf16(af, bfr, acc[n], 0, 0, 0);
        }
    }
    // C/D layout: col = lane&15, row = (lane>>4)*4 + i   [m89/m91 verified]
    const int crow = row0 + (lane >> 4) * 4;
    const int ccol = lane & 15;
#pragma unroll
    for (int n = 0; n < NTILES; n++) {
        const int c = (ntile0 + n) * 16 + ccol;
        if (c < M) {
            if (OUTF32) {
                float* C = (float*)Cv;
#pragma unroll
                for (int i = 0; i < 4; i++) C[(size_t)(crow + i) * M + c] = acc[n][i];
            } else {
                unsigned short* C = (unsigned short*)Cv;
#pragma unroll
                for (int i = 0; i < 4; i++) C[(size_t)(crow + i) * M + c] = f2bf(acc[n][i]);
            }
        }
    }
}

// ---------------- Aggregation (gather over CSR), F = 256, bf16 in fp32 out ---
__global__ void k_agg256b(const ushort4* __restrict__ XWb, const int* __restrict__ row_ptr,
                          const int* __restrict__ ssrc, const float* __restrict__ dinv,
                          const float* __restrict__ bias, float4* __restrict__ H) {
    const int wave = threadIdx.x >> 6;
    const int lane = threadIdx.x & 63;
    const int node = blockIdx.x * 4 + wave;   // 50000 = 12500 * 4
    const float dd = dinv[node];
    const float sw = dd * dd;
    ushort4 v = XWb[node * 64 + lane];
    float4 acc;
    acc.x = sw * bf2f(v.x); acc.y = sw * bf2f(v.y);
    acc.z = sw * bf2f(v.z); acc.w = sw * bf2f(v.w);
    const int s0 = row_ptr[node], s1 = row_ptr[node + 1];
    for (int j = s0; j < s1; j++) {
        const int s = ssrc[j];
        const float w = dinv[s] * dd;
        ushort4 u = XWb[s * 64 + lane];
        acc.x += w * bf2f(u.x); acc.y += w * bf2f(u.y);
        acc.z += w * bf2f(u.z); acc.w += w * bf2f(u.w);
    }
    const int f = lane * 4;
    acc.x += bias[f + 0]; acc.y += bias[f + 1];
    acc.z += bias[f + 2]; acc.w += bias[f + 3];
    H[node * 64 + lane] = acc;
}

// ---------------- Aggregation, F = 40 (one wave per node), fp32 ----------------
__global__ void k_agg40(const float* __restrict__ XW, const int* __restrict__ row_ptr,
                        const int* __restrict__ ssrc, const float* __restrict__ dinv,
                        const float* __restrict__ bias, float* __restrict__ H) {
    const int wave = threadIdx.x >> 6;
    const int lane = threadIdx.x & 63;
    const int node = blockIdx.x * 4 + wave;
    const float dd = dinv[node];
    float acc = 0.f;
    if (lane < NCLS) acc = dd * dd * XW[node * NCLS + lane];
    const int s0 = row_ptr[node], s1 = row_ptr[node + 1];
    for (int j = s0; j < s1; j++) {
        const int s = ssrc[j];
        const float w = dinv[s] * dd;
        if (lane < NCLS) acc += w * XW[s * NCLS + lane];
    }
    if (lane < NCLS) H[node * NCLS + lane] = acc + bias[lane];
}

// ---------------- BatchNorm (training stats) + ReLU ----------------
__global__ void k_bnstats(const float* __restrict__ H, float* __restrict__ gsum,
                          float* __restrict__ gsq) {
    const int f = threadIdx.x;       // 256 features
    const int r0 = blockIdx.x * 64;
    int r1 = r0 + 64; if (r1 > N_NODES) r1 = N_NODES;
    float s = 0.f, q = 0.f;
    for (int r = r0; r < r1; r++) {
        float v = H[r * HIDDEN + f];
        s += v; q += v * v;
    }
    atomicAdd(&gsum[f], s);
    atomicAdd(&gsq[f], q);
}

__global__ void k_bnprep(const float* __restrict__ gsum, const float* __restrict__ gsq,
                         const float* __restrict__ g, const float* __restrict__ be,
                         float* __restrict__ scale, float* __restrict__ shift) {
    const int f = threadIdx.x;
    const float inv_n = 1.0f / (float)N_NODES;
    float mean = gsum[f] * inv_n;
    float var = gsq[f] * inv_n - mean * mean;
    var = fmaxf(var, 0.f);
    float sc = g[f] * rsqrtf(var + BN_EPS);
    scale[f] = sc;
    shift[f] = be[f] - mean * sc;
}

// BN + ReLU + bf16 cast (next GEMM input); fp32 H not written back.
__global__ void k_bnapply_bf(const float4* __restrict__ H, const float* __restrict__ scale,
                             const float* __restrict__ shift, ushort4* __restrict__ Hb) {
    const int i = blockIdx.x * blockDim.x + threadIdx.x;  // over N*64 float4s
    if (i >= N_NODES * 64) return;
    const int f = (i & 63) * 4;
    float4 v = H[i];
    ushort4 o;
    o.x = f2bf(fmaxf(v.x * scale[f + 0] + shift[f + 0], 0.f));
    o.y = f2bf(fmaxf(v.y * scale[f + 1] + shift[f + 1], 0.f));
    o.z = f2bf(fmaxf(v.z * scale[f + 2] + shift[f + 2], 0.f));
    o.w = f2bf(fmaxf(v.w * scale[f + 3] + shift[f + 3], 0.f));
    Hb[i] = o;
}

// ---------------- log_softmax over 40 classes ----------------
__global__ void k_lsm(const float* __restrict__ H3, float* __restrict__ out) {
    const int n = blockIdx.x * blockDim.x + threadIdx.x;
    if (n >= N_NODES) return;
    const float* row = H3 + n * NCLS;
    float m = -1e30f;
    for (int c = 0; c < NCLS; c++) m = fmaxf(m, row[c]);
    float s = 0.f;
    for (int c = 0; c < NCLS; c++) s += expf(row[c] - m);
    const float lse = m + logf(s);
    for (int c = 0; c < NCLS; c++) out[n * NCLS + c] = row[c] - lse;
}

extern "C" void kernel_launch(void* const* d_in, const int* in_sizes, int n_in,
                              void* d_out, int out_size, void* d_ws, size_t ws_size,
                              hipStream_t stream) {
    const float* x   = (const float*)d_in[0];
    const int*   ei  = (const int*)d_in[1];
    const float* W1  = (const float*)d_in[2];
    const float* b1  = (const float*)d_in[3];
    const float* g1  = (const float*)d_in[4];
    const float* be1 = (const float*)d_in[5];
    const float* W2  = (const float*)d_in[6];
    const float* b2  = (const float*)d_in[7];
    const float* g2  = (const float*)d_in[8];
    const float* be2 = (const float*)d_in[9];
    const float* W3  = (const float*)d_in[10];
    const float* b3  = (const float*)d_in[11];
    float* out = (float*)d_out;

    const int* e_src = ei;
    const int* e_dst = ei + N_EDGES;

    // ---- workspace layout (all offsets multiples of 16 B) ----
    char* w = (char*)d_ws;
    unsigned short* XWb = (unsigned short*)w;  w += (size_t)N_NODES * HIDDEN * 2;   // 25.6 MB (also fp32 XW3: 8 MB)
    float* H      = (float*)w;                 w += (size_t)N_NODES * HIDDEN * 4;   // 51.2 MB
    unsigned short* Hb = (unsigned short*)w;   w += (size_t)N_NODES * HIDDEN * 2;   // 25.6 MB (xb aliases: dead after L1 GEMM)
    float* dinv   = (float*)w;                 w += (size_t)N_NODES * 4;
    int*   counts = (int*)w;                   w += (size_t)N_NODES * 4;
    int*   rowp   = (int*)w;                   w += (size_t)(N_NODES + 4) * 4;
    int*   cursor = (int*)w;                   w += (size_t)N_NODES * 4;
    int*   ssrc   = (int*)w;                   w += (size_t)N_EDGES * 4;
    int*   partials=(int*)w;                   w += 256 * 4;
    float* gsum   = (float*)w;                 w += 256 * 4;
    float* gsq    = (float*)w;                 w += 256 * 4;
    float* scale  = (float*)w;                 w += 256 * 4;
    float* shift  = (float*)w;                 w += 256 * 4;
    unsigned short* W1p = (unsigned short*)w;  w += (size_t)16 * 4 * 64 * 8 * 2;    // 64 KB
    unsigned short* W2p = (unsigned short*)w;  w += (size_t)16 * 8 * 64 * 8 * 2;    // 128 KB
    unsigned short* W3p = (unsigned short*)w;  w += (size_t)3 * 8 * 64 * 8 * 2;     // 24 KB

    unsigned short* xb = Hb;  // alias: x_bf16 only live until L1 GEMM; Hb written after

    const int EB = (N_EDGES + 255) / 256;
    const int NB = (N_NODES + 255) / 256;

    // ---- CSR build ----
    hipMemsetAsync(counts, 0, (size_t)N_NODES * 4, stream);
    k_hist<<<EB, 256, 0, stream>>>(e_dst, counts);
    k_scan_local<<<SCAN_NB, SCAN_B, 0, stream>>>(counts, rowp, partials);
    k_scan_add<<<SCAN_NB, SCAN_B, 0, stream>>>(rowp, cursor, partials);
    k_dinv<<<NB, 256, 0, stream>>>(counts, dinv);
    k_scatter<<<EB, 256, 0, stream>>>(e_src, e_dst, cursor, ssrc);

    // ---- dtype prep ----
    k_cvt_bf16<<<(N_NODES * IN_FEAT / 4 + 255) / 256, 256, 0, stream>>>(
        (const float4*)x, (ushort4*)xb, N_NODES * IN_FEAT / 4);
    k_packB<<<dim3(16, IN_FEAT / 32), 64, 0, stream>>>(W1, W1p, IN_FEAT, HIDDEN);
    k_packB<<<dim3(16, HIDDEN / 32), 64, 0, stream>>>(W2, W2p, HIDDEN, HIDDEN);
    k_packB<<<dim3(3, HIDDEN / 32), 64, 0, stream>>>(W3, W3p, HIDDEN, NCLS);

    // ---- layer 1 ----
    k_gemm_mfma<IN_FEAT, 4, false><<<N_NODES / 16, 256, 0, stream>>>(
        (const short*)xb, (const short*)W1p, XWb, HIDDEN);
    k_agg256b<<<N_NODES / 4, 256, 0, stream>>>((const ushort4*)XWb, rowp, ssrc, dinv, b1, (float4*)H);
    hipMemsetAsync(gsum, 0, 2 * 256 * 4, stream);
    k_bnstats<<<(N_NODES + 63) / 64, 256, 0, stream>>>(H, gsum, gsq);
    k_bnprep<<<1, 256, 0, stream>>>(gsum, gsq, g1, be1, scale, shift);
    k_bnapply_bf<<<(N_NODES * 64 + 255) / 256, 256, 0, stream>>>(
        (const float4*)H, scale, shift, (ushort4*)Hb);

    // ---- layer 2 ----
    k_gemm_mfma<HIDDEN, 4, false><<<N_NODES / 16, 256, 0, stream>>>(
        (const short*)Hb, (const short*)W2p, XWb, HIDDEN);
    k_agg256b<<<N_NODES / 4, 256, 0, stream>>>((const ushort4*)XWb, rowp, ssrc, dinv, b2, (float4*)H);
    hipMemsetAsync(gsum, 0, 2 * 256 * 4, stream);
    k_bnstats<<<(N_NODES + 63) / 64, 256, 0, stream>>>(H, gsum, gsq);
    k_bnprep<<<1, 256, 0, stream>>>(gsum, gsq, g2, be2, scale, shift);
    k_bnapply_bf<<<(N_NODES * 64 + 255) / 256, 256, 0, stream>>>(
        (const float4*)H, scale, shift, (ushort4*)Hb);

    // ---- output layer ----
    float* XW3 = (float*)XWb;  // 8 MB fp32, reuses XWb region (last read: L2 agg, done)
    k_gemm_mfma<HIDDEN, 3, true><<<N_NODES / 16, 64, 0, stream>>>(
        (const short*)Hb, (const short*)W3p, XW3, NCLS);
    float* H3 = H;
    k_agg40<<<N_NODES / 4, 256, 0, stream>>>(XW3, rowp, ssrc, dinv, b3, H3);
    k_lsm<<<(N_NODES + 255) / 256, 256, 0, stream>>>(H3, out);
}

// Round 6
// 371.511 us; speedup vs baseline: 3.2735x; 1.2259x over previous
//
#include <hip/hip_runtime.h>
#include <hip/hip_bf16.h>

#define N_NODES 50000
#define N_EDGES 320000
#define IN_FEAT 128
#define HIDDEN  256
#define NCLS    40
#define BN_EPS  1e-5f

#define SCAN_B  256
#define SCAN_NB ((N_NODES + SCAN_B - 1) / SCAN_B)   // 196
#define AGG_NB  (N_NODES / 16)                      // 3125 blocks, 16 nodes each

typedef __attribute__((ext_vector_type(8))) short bf16x8;
typedef __attribute__((ext_vector_type(4))) float f32x4;
typedef __attribute__((ext_vector_type(8))) unsigned short ushort8;

__device__ __forceinline__ unsigned short f2bf(float f) {
    union { float f; unsigned u; } a; a.f = f;
    unsigned r = a.u + 0x7fff + ((a.u >> 16) & 1);   // RNE
    return (unsigned short)(r >> 16);
}
__device__ __forceinline__ float bf2f(unsigned short u) {
    union { unsigned u; float f; } a; a.u = ((unsigned)u) << 16;
    return a.f;
}

// ---------------- CSR build ----------------
__global__ void k_hist(const int* __restrict__ dst, int* __restrict__ counts) {
    int e = blockIdx.x * blockDim.x + threadIdx.x;
    if (e < N_EDGES) atomicAdd(&counts[dst[e]], 1);
}

__global__ __launch_bounds__(SCAN_B) void k_scan_local(const int* __restrict__ counts,
                                                       int* __restrict__ rowp,
                                                       int* __restrict__ partials) {
    __shared__ int s[SCAN_B];
    const int tid = threadIdx.x;
    const int i = blockIdx.x * SCAN_B + tid;
    int v = (i < N_NODES) ? counts[i] : 0;
    s[tid] = v;
    __syncthreads();
    for (int off = 1; off < SCAN_B; off <<= 1) {
        int t = (tid >= off) ? s[tid - off] : 0;
        __syncthreads();
        s[tid] += t;
        __syncthreads();
    }
    if (i < N_NODES) rowp[i] = s[tid] - v;  // exclusive
    if (tid == SCAN_B - 1) partials[blockIdx.x] = s[SCAN_B - 1];
}

// Adds block offset; mirrors into cursor; also computes dinv (fused k_dinv).
__global__ __launch_bounds__(SCAN_B) void k_scan_add(int* __restrict__ rowp,
                                                     int* __restrict__ cursor,
                                                     const int* __restrict__ partials,
                                                     const int* __restrict__ counts,
                                                     float* __restrict__ dinv) {
    __shared__ int s[SCAN_B];
    const int tid = threadIdx.x;
    const int b = blockIdx.x;
    int v = (tid < b) ? partials[tid] : 0;   // SCAN_NB <= 256
    s[tid] = v;
    __syncthreads();
    for (int off = SCAN_B / 2; off > 0; off >>= 1) {
        if (tid < off) s[tid] += s[tid + off];
        __syncthreads();
    }
    const int offset = s[0];
    const int i = b * SCAN_B + tid;
    if (i < N_NODES) {
        int r = rowp[i] + offset;
        rowp[i] = r;
        cursor[i] = r;
        dinv[i] = rsqrtf(1.0f + (float)counts[i]);
    }
    if (b == 0 && tid == 0) rowp[N_NODES] = N_EDGES;
}

__global__ void k_scatter(const int* __restrict__ src, const int* __restrict__ dst,
                          int* __restrict__ cursor, int* __restrict__ ssrc) {
    int e = blockIdx.x * blockDim.x + threadIdx.x;
    if (e < N_EDGES) {
        int d = dst[e];
        int p = atomicAdd(&cursor[d], 1);
        ssrc[p] = src[e];
    }
}

// ---------------- pack W[K,M] fp32 -> MFMA B-frag layout bf16 ----------------
__global__ void k_packB(const float* __restrict__ W, unsigned short* __restrict__ Bp,
                        int K, int M) {
    const int nt = blockIdx.x, kt = blockIdx.y, lane = threadIdx.x;
    const int nkt = gridDim.y;
    const int n = nt * 16 + (lane & 15);
    const int kb = kt * 32 + (lane >> 4) * 8;
    unsigned short* dst = Bp + (((size_t)nt * nkt + kt) * 64 + lane) * 8;
#pragma unroll
    for (int j = 0; j < 8; j++)
        dst[j] = (n < M) ? f2bf(W[(size_t)(kb + j) * M + n]) : (unsigned short)0;
}

// ---------------- MFMA GEMM: C[N,M] = A[N,K] @ B[K,M] ----------------
// A row-major (fp32 if AF32, converted on load; else bf16). Bp packed frags.
template <int K_, int NTILES, bool AF32, bool OUTF32>
__global__ __launch_bounds__(256) void k_gemm_mfma(const void* __restrict__ Av,
                                                   const short* __restrict__ Bp,
                                                   void* __restrict__ Cv, int M) {
    const int wave = threadIdx.x >> 6;
    const int lane = threadIdx.x & 63;
    const int row0 = blockIdx.x * 16;
    const int ntile0 = wave * NTILES;
    constexpr int nkt = K_ / 32;
    const size_t abase = (size_t)(row0 + (lane & 15)) * K_ + (lane >> 4) * 8;
    f32x4 acc[NTILES] = {};
#pragma unroll
    for (int kt = 0; kt < nkt; kt++) {
        bf16x8 af;
        if (AF32) {
            const float* A32 = (const float*)Av;
            float4 p0 = *(const float4*)(A32 + abase + kt * 32);
            float4 p1 = *(const float4*)(A32 + abase + kt * 32 + 4);
            af[0] = (short)f2bf(p0.x); af[1] = (short)f2bf(p0.y);
            af[2] = (short)f2bf(p0.z); af[3] = (short)f2bf(p0.w);
            af[4] = (short)f2bf(p1.x); af[5] = (short)f2bf(p1.y);
            af[6] = (short)f2bf(p1.z); af[7] = (short)f2bf(p1.w);
        } else {
            const short* A16 = (const short*)Av;
            af = *(const bf16x8*)(A16 + abase + kt * 32);
        }
#pragma unroll
        for (int n = 0; n < NTILES; n++) {
            bf16x8 bfr = *(const bf16x8*)(Bp + (((size_t)(ntile0 + n) * nkt + kt) * 64 + lane) * 8);
            acc[n] = __builtin_amdgcn_mfma_f32_16x16x32_bf16(af, bfr, acc[n], 0, 0, 0);
        }
    }
    const int crow = row0 + (lane >> 4) * 4;   // C/D: col=lane&15, row=(lane>>4)*4+i
    const int ccol = lane & 15;
#pragma unroll
    for (int n = 0; n < NTILES; n++) {
        const int c = (ntile0 + n) * 16 + ccol;
        if (c < M) {
            if (OUTF32) {
                float* C = (float*)Cv;
#pragma unroll
                for (int i = 0; i < 4; i++) C[(size_t)(crow + i) * M + c] = acc[n][i];
            } else {
                unsigned short* C = (unsigned short*)Cv;
#pragma unroll
                for (int i = 0; i < 4; i++) C[(size_t)(crow + i) * M + c] = f2bf(acc[n][i]);
            }
        }
    }
}

// ---------------- Aggregation + BN-stats, F=256, bf16 in / bf16 out ----------
// 16 nodes/block (4 waves x 4 nodes). Per-block stats partials: [2][256] floats.
__global__ __launch_bounds__(256) void k_agg_bn(const ushort4* __restrict__ XWb,
                                                const int* __restrict__ row_ptr,
                                                const int* __restrict__ ssrc,
                                                const float* __restrict__ dinv,
                                                const float* __restrict__ bias,
                                                ushort4* __restrict__ Hbf,
                                                float* __restrict__ bnp) {
    __shared__ float red[2][4][256];
    const int wave = threadIdx.x >> 6;
    const int lane = threadIdx.x & 63;
    const int f = lane * 4;
    const float4 bi = *(const float4*)(bias + f);
    float s0a = 0.f, s1a = 0.f, s2a = 0.f, s3a = 0.f;   // sum per feature c
    float q0a = 0.f, q1a = 0.f, q2a = 0.f, q3a = 0.f;   // sumsq

#pragma unroll
    for (int nn = 0; nn < 4; nn++) {
        const int node = blockIdx.x * 16 + wave * 4 + nn;
        const float dd = dinv[node];
        const float sw = dd * dd;
        ushort4 v = XWb[node * 64 + lane];
        float a0 = sw * bf2f(v.x), a1 = sw * bf2f(v.y);
        float a2 = sw * bf2f(v.z), a3 = sw * bf2f(v.w);
        const int e0 = row_ptr[node], e1 = row_ptr[node + 1];
        int j = e0;
        for (; j + 3 < e1; j += 4) {
            const int i0 = ssrc[j], i1 = ssrc[j + 1], i2 = ssrc[j + 2], i3 = ssrc[j + 3];
            const float w0 = dinv[i0] * dd, w1 = dinv[i1] * dd;
            const float w2 = dinv[i2] * dd, w3 = dinv[i3] * dd;
            ushort4 u0 = XWb[i0 * 64 + lane];
            ushort4 u1 = XWb[i1 * 64 + lane];
            ushort4 u2 = XWb[i2 * 64 + lane];
            ushort4 u3 = XWb[i3 * 64 + lane];
            a0 += w0 * bf2f(u0.x) + w1 * bf2f(u1.x) + w2 * bf2f(u2.x) + w3 * bf2f(u3.x);
            a1 += w0 * bf2f(u0.y) + w1 * bf2f(u1.y) + w2 * bf2f(u2.y) + w3 * bf2f(u3.y);
            a2 += w0 * bf2f(u0.z) + w1 * bf2f(u1.z) + w2 * bf2f(u2.z) + w3 * bf2f(u3.z);
            a3 += w0 * bf2f(u0.w) + w1 * bf2f(u1.w) + w2 * bf2f(u2.w) + w3 * bf2f(u3.w);
        }
        for (; j < e1; j++) {
            const int s = ssrc[j];
            const float w = dinv[s] * dd;
            ushort4 u = XWb[s * 64 + lane];
            a0 += w * bf2f(u.x); a1 += w * bf2f(u.y);
            a2 += w * bf2f(u.z); a3 += w * bf2f(u.w);
        }
        a0 += bi.x; a1 += bi.y; a2 += bi.z; a3 += bi.w;
        ushort4 o;
        o.x = f2bf(a0); o.y = f2bf(a1); o.z = f2bf(a2); o.w = f2bf(a3);
        Hbf[node * 64 + lane] = o;
        s0a += a0; s1a += a1; s2a += a2; s3a += a3;
        q0a += a0 * a0; q1a += a1 * a1; q2a += a2 * a2; q3a += a3 * a3;
    }
    red[0][wave][f + 0] = s0a; red[0][wave][f + 1] = s1a;
    red[0][wave][f + 2] = s2a; red[0][wave][f + 3] = s3a;
    red[1][wave][f + 0] = q0a; red[1][wave][f + 1] = q1a;
    red[1][wave][f + 2] = q2a; red[1][wave][f + 3] = q3a;
    __syncthreads();
    const int t = threadIdx.x;
    float ss = red[0][0][t] + red[0][1][t] + red[0][2][t] + red[0][3][t];
    float qq = red[1][0][t] + red[1][1][t] + red[1][2][t] + red[1][3][t];
    bnp[(size_t)blockIdx.x * 512 + t]       = ss;
    bnp[(size_t)blockIdx.x * 512 + 256 + t] = qq;
}

// ---------------- reduce BN partials -> gsum/gsq ----------------
__global__ __launch_bounds__(256) void k_bnreduce(const float* __restrict__ bnp,
                                                  float* __restrict__ gsum,
                                                  float* __restrict__ gsq) {
    const int t = threadIdx.x;
    const int b = blockIdx.x;                 // 32 blocks
    const int per = (AGG_NB + 31) / 32;       // 98
    int r0 = b * per, r1 = r0 + per; if (r1 > AGG_NB) r1 = AGG_NB;
    float s = 0.f, q = 0.f;
    for (int r = r0; r < r1; r++) {
        s += bnp[(size_t)r * 512 + t];
        q += bnp[(size_t)r * 512 + 256 + t];
    }
    atomicAdd(&gsum[t], s);
    atomicAdd(&gsq[t], q);
}

__global__ void k_bnprep(const float* __restrict__ gsum, const float* __restrict__ gsq,
                         const float* __restrict__ g, const float* __restrict__ be,
                         float* __restrict__ scale, float* __restrict__ shift) {
    const int f = threadIdx.x;
    const float inv_n = 1.0f / (float)N_NODES;
    float mean = gsum[f] * inv_n;
    float var = gsq[f] * inv_n - mean * mean;
    var = fmaxf(var, 0.f);
    float sc = g[f] * rsqrtf(var + BN_EPS);
    scale[f] = sc;
    shift[f] = be[f] - mean * sc;
}

// BN + ReLU on bf16 H -> bf16 (next GEMM input)
__global__ void k_bnapply16(const ushort8* __restrict__ Hbf, const float* __restrict__ scale,
                            const float* __restrict__ shift, ushort8* __restrict__ Hb2) {
    const int i = blockIdx.x * blockDim.x + threadIdx.x;  // over N*32 ushort8s
    if (i >= N_NODES * 32) return;
    const int f = (i & 31) * 8;
    ushort8 v = Hbf[i];
    ushort8 o;
#pragma unroll
    for (int j = 0; j < 8; j++)
        o[j] = f2bf(fmaxf(bf2f(v[j]) * scale[f + j] + shift[f + j], 0.f));
    Hb2[i] = o;
}

// ---------------- output: gather F=40 + log_softmax, one wave/node -----------
__global__ __launch_bounds__(256) void k_out(const float* __restrict__ XW,
                                             const int* __restrict__ row_ptr,
                                             const int* __restrict__ ssrc,
                                             const float* __restrict__ dinv,
                                             const float* __restrict__ bias,
                                             float* __restrict__ out) {
    const int wave = threadIdx.x >> 6;
    const int lane = threadIdx.x & 63;
    const int node = blockIdx.x * 4 + wave;
    const float dd = dinv[node];
    const bool act = lane < NCLS;
    float acc = 0.f;
    if (act) acc = dd * dd * XW[node * NCLS + lane];
    const int e0 = row_ptr[node], e1 = row_ptr[node + 1];
    int j = e0;
    for (; j + 1 < e1; j += 2) {
        const int i0 = ssrc[j], i1 = ssrc[j + 1];
        const float w0 = dinv[i0] * dd, w1 = dinv[i1] * dd;
        float v0 = 0.f, v1 = 0.f;
        if (act) { v0 = XW[i0 * NCLS + lane]; v1 = XW[i1 * NCLS + lane]; }
        acc += w0 * v0 + w1 * v1;
    }
    for (; j < e1; j++) {
        const int s = ssrc[j];
        const float w = dinv[s] * dd;
        if (act) acc += w * XW[s * NCLS + lane];
    }
    if (act) acc += bias[lane];
    float m = act ? acc : -1e30f;
#pragma unroll
    for (int off = 32; off > 0; off >>= 1) m = fmaxf(m, __shfl_xor(m, off));
    float e = act ? expf(acc - m) : 0.f;
#pragma unroll
    for (int off = 32; off > 0; off >>= 1) e += __shfl_xor(e, off);
    const float lse = m + logf(e);
    if (act) out[node * NCLS + lane] = acc - lse;
}

extern "C" void kernel_launch(void* const* d_in, const int* in_sizes, int n_in,
                              void* d_out, int out_size, void* d_ws, size_t ws_size,
                              hipStream_t stream) {
    const float* x   = (const float*)d_in[0];
    const int*   ei  = (const int*)d_in[1];
    const float* W1  = (const float*)d_in[2];
    const float* b1  = (const float*)d_in[3];
    const float* g1  = (const float*)d_in[4];
    const float* be1 = (const float*)d_in[5];
    const float* W2  = (const float*)d_in[6];
    const float* b2  = (const float*)d_in[7];
    const float* g2  = (const float*)d_in[8];
    const float* be2 = (const float*)d_in[9];
    const float* W3  = (const float*)d_in[10];
    const float* b3  = (const float*)d_in[11];
    float* out = (float*)d_out;

    const int* e_src = ei;
    const int* e_dst = ei + N_EDGES;

    // ---- workspace layout ----
    char* w = (char*)d_ws;
    unsigned short* XWb = (unsigned short*)w;  w += (size_t)N_NODES * HIDDEN * 2;   // 25.6 MB (also fp32 XW3: 8 MB)
    unsigned short* Hbf = (unsigned short*)w;  w += (size_t)N_NODES * HIDDEN * 2;   // 25.6 MB
    unsigned short* Hb2 = (unsigned short*)w;  w += (size_t)N_NODES * HIDDEN * 2;   // 25.6 MB
    float* bnp    = (float*)w;                 w += (size_t)AGG_NB * 512 * 4;       // 6.4 MB
    float* dinv   = (float*)w;                 w += (size_t)N_NODES * 4;
    int*   counts = (int*)w;                   w += (size_t)N_NODES * 4;
    int*   rowp   = (int*)w;                   w += (size_t)(N_NODES + 4) * 4;
    int*   cursor = (int*)w;                   w += (size_t)N_NODES * 4;
    int*   ssrc   = (int*)w;                   w += (size_t)N_EDGES * 4;
    int*   partials=(int*)w;                   w += 256 * 4;
    float* gsum   = (float*)w;                 w += 256 * 4;
    float* gsq    = (float*)w;                 w += 256 * 4;
    float* scale  = (float*)w;                 w += 256 * 4;
    float* shift  = (float*)w;                 w += 256 * 4;
    unsigned short* W1p = (unsigned short*)w;  w += (size_t)16 * 4 * 64 * 8 * 2;    // 64 KB
    unsigned short* W2p = (unsigned short*)w;  w += (size_t)16 * 8 * 64 * 8 * 2;    // 128 KB
    unsigned short* W3p = (unsigned short*)w;  w += (size_t)3 * 8 * 64 * 8 * 2;     // 24 KB

    const int EB = (N_EDGES + 255) / 256;

    // ---- CSR build ----
    hipMemsetAsync(counts, 0, (size_t)N_NODES * 4, stream);
    k_hist<<<EB, 256, 0, stream>>>(e_dst, counts);
    k_scan_local<<<SCAN_NB, SCAN_B, 0, stream>>>(counts, rowp, partials);
    k_scan_add<<<SCAN_NB, SCAN_B, 0, stream>>>(rowp, cursor, partials, counts, dinv);
    k_scatter<<<EB, 256, 0, stream>>>(e_src, e_dst, cursor, ssrc);

    // ---- weight packs ----
    k_packB<<<dim3(16, IN_FEAT / 32), 64, 0, stream>>>(W1, W1p, IN_FEAT, HIDDEN);
    k_packB<<<dim3(16, HIDDEN / 32), 64, 0, stream>>>(W2, W2p, HIDDEN, HIDDEN);
    k_packB<<<dim3(3, HIDDEN / 32), 64, 0, stream>>>(W3, W3p, HIDDEN, NCLS);

    // ---- layer 1 ----
    k_gemm_mfma<IN_FEAT, 4, true, false><<<N_NODES / 16, 256, 0, stream>>>(
        x, (const short*)W1p, XWb, HIDDEN);
    k_agg_bn<<<AGG_NB, 256, 0, stream>>>((const ushort4*)XWb, rowp, ssrc, dinv, b1,
                                         (ushort4*)Hbf, bnp);
    hipMemsetAsync(gsum, 0, 2 * 256 * 4, stream);
    k_bnreduce<<<32, 256, 0, stream>>>(bnp, gsum, gsq);
    k_bnprep<<<1, 256, 0, stream>>>(gsum, gsq, g1, be1, scale, shift);
    k_bnapply16<<<(N_NODES * 32 + 255) / 256, 256, 0, stream>>>(
        (const ushort8*)Hbf, scale, shift, (ushort8*)Hb2);

    // ---- layer 2 ----
    k_gemm_mfma<HIDDEN, 4, false, false><<<N_NODES / 16, 256, 0, stream>>>(
        Hb2, (const short*)W2p, XWb, HIDDEN);
    k_agg_bn<<<AGG_NB, 256, 0, stream>>>((const ushort4*)XWb, rowp, ssrc, dinv, b2,
                                         (ushort4*)Hbf, bnp);
    hipMemsetAsync(gsum, 0, 2 * 256 * 4, stream);
    k_bnreduce<<<32, 256, 0, stream>>>(bnp, gsum, gsq);
    k_bnprep<<<1, 256, 0, stream>>>(gsum, gsq, g2, be2, scale, shift);
    k_bnapply16<<<(N_NODES * 32 + 255) / 256, 256, 0, stream>>>(
        (const ushort8*)Hbf, scale, shift, (ushort8*)Hb2);

    // ---- output layer ----
    float* XW3 = (float*)XWb;  // 8 MB fp32, reuses XWb region
    k_gemm_mfma<HIDDEN, 3, false, true><<<N_NODES / 16, 64, 0, stream>>>(
        Hb2, (const short*)W3p, XW3, NCLS);
    k_out<<<N_NODES / 4, 256, 0, stream>>>(XW3, rowp, ssrc, dinv, b3, out);
}